// Round 18
// baseline (230.718 us; speedup 1.0000x reference)
//
#include <hip/hip_runtime.h>
#include <hip/hip_bf16.h>

// Network_70918499991665: 12-layer implicit-map extractor, fwd + analytic grad.
// Round 17: r16 base + K-loop VALU elimination: named stream base pointers
// xa0..xa3 (stream LDS offsets 30976*s B exceed 16-bit ds imm for s>=2 ->
// compiler emitted per-iter v_adds under unroll-1; named pointers make every
// af read imm-offset) + bB global loads issued BEFORE af LDS reads (L2 latency
// hides under LDS latency + burst1). No register-count change (spill wall).

#define NPTS 4096
#define XS 968          // X LDS row stride in u16

typedef unsigned short u16;
typedef unsigned int   u32;
typedef __attribute__((ext_vector_type(8))) __bf16 bf16x8;
typedef __attribute__((ext_vector_type(4))) float  f32x4;

__device__ __forceinline__ float bf2f(u16 h) {
  return __uint_as_float(((u32)h) << 16);
}
__device__ __forceinline__ u16 f2bf(float f) {
  u32 u = __float_as_uint(f);
  u += 0x7fff + ((u >> 16) & 1);   // RNE
  return (u16)(u >> 16);
}

// softplus(100x)/100 and sigmoid(100x), numerically stable
__device__ __forceinline__ void act_sp_sg(float pre, float& sp, float& sg) {
  float z = 100.f * pre;
  float e = __expf(-fabsf(z));
  float r = 1.f / (1.f + e);
  float l = __logf(1.f + e) * 0.01f;
  if (z >= 0.f) { sg = r;       sp = pre + l; }
  else          { sg = 1.f - r; sp = l; }
}

// ---------------- weight-norm + pack into MFMA B-fragment order.
struct WLayer { const float* v; const float* g; int Cin, Cout, KS, MF; size_t woff; };
struct WAll { WLayer L[11]; };

__global__ __launch_bounds__(256)
void wnormF(WAll wa, u16* __restrict__ Wf) {
  const WLayer L = wa.L[blockIdx.y];
  const int cb = blockIdx.x;
  if (cb >= L.MF) return;
  __shared__ float red[16][17];
  __shared__ float scl[16];
  const int t = threadIdx.x;
  {
    // coalesced: consecutive lanes read consecutive k of the SAME col row
    const int col16 = t >> 4, kt = t & 15;
    const int col = cb * 16 + col16;
    float ss = 0.f;
    if (col < L.Cout)
      for (int k = kt; k < L.Cin; k += 16) {
        float x = L.v[(size_t)col * L.Cin + k]; ss += x * x;
      }
    red[col16][kt] = ss;
  }
  __syncthreads();
  if (t < 16) {
    float s = 0.f;
#pragma unroll
    for (int j = 0; j < 16; ++j) s += red[t][j];
    const int c = cb * 16 + t;
    scl[t] = (c < L.Cout) ? L.g[c] / sqrtf(s) : 0.f;
  }
  __syncthreads();
  u32* dst = (u32*)(Wf + L.woff);
  const int lane = t >> 2, q = t & 3;
  const int vcol = cb * 16 + (lane & 15);
  const float sc = scl[lane & 15];
  const float* vrow = L.v + (size_t)vcol * L.Cin;
  const bool cok = vcol < L.Cout;
  for (int ks = 0; ks < L.KS; ++ks) {
    const int k0 = ks * 32 + (lane >> 4) * 8 + q * 2;
    u16 lo = 0, hi16 = 0;
    if (cok) {
      if (k0 < L.Cin)     lo   = f2bf(vrow[k0] * sc);
      if (k0 + 1 < L.Cin) hi16 = f2bf(vrow[k0 + 1] * sc);
    }
    dst[(size_t)(ks * L.MF + cb) * 128 + t] = (u32)lo | ((u32)hi16 << 16);
  }
}

// ---------------- fused network ----------------
#define NWAVE 16
struct FusedArgs {
  size_t woff[11];
  const float* bias[11];
  const float* v10; const float* g10; const float* b10;
};

// Mid layer: X rows 0..63 = 4 streams x 16 points; in cols [0,KS*32),
// out cols [0, MF*16) == COUT written in-place after barrier.
template<int KS, int MF, int COUT>
__device__ __forceinline__ void layer_mid(const u16* __restrict__ Wf,
                                          const float* __restrict__ bias,
                                          u16* __restrict__ X,
                                          int w, int lane, int lcol, int hi) {
  static_assert(COUT == MF * 16, "mid layers have exact tiling");
  constexpr int NF = (MF + NWAVE - 1) / NWAVE;
  f32x4 acc[4][NF];
#pragma unroll
  for (int s = 0; s < 4; ++s)
#pragma unroll
    for (int i = 0; i < NF; ++i) acc[s][i] = (f32x4){0.f, 0.f, 0.f, 0.f};

  const u16* wp = Wf + lane * 8;
  const u16* xa0 = X + lcol * XS + hi * 8;
  const u16* xa1 = xa0 + 16 * XS;
  const u16* xa2 = xa0 + 32 * XS;
  const u16* xa3 = xa0 + 48 * XS;
  bf16x8 bA[NF], bB[NF];
#pragma unroll
  for (int i = 0; i < NF; ++i)
    if (w + NWAVE * i < MF)
      bA[i] = *(const bf16x8*)(wp + (size_t)(w + NWAVE * i) * 512);

#pragma unroll 1
  for (int ks = 0; ks < KS; ks += 2) {
    // global loads first: L2 latency hides under LDS reads + burst1
#pragma unroll
    for (int i = 0; i < NF; ++i)
      if (w + NWAVE * i < MF)
        bB[i] = *(const bf16x8*)(wp + (size_t)((ks + 1) * MF + w + NWAVE * i) * 512);
    bf16x8 af[4];
    af[0] = *(const bf16x8*)(xa0 + ks * 32);
    af[1] = *(const bf16x8*)(xa1 + ks * 32);
    af[2] = *(const bf16x8*)(xa2 + ks * 32);
    af[3] = *(const bf16x8*)(xa3 + ks * 32);
    __builtin_amdgcn_s_setprio(1);
#pragma unroll
    for (int i = 0; i < NF; ++i)
      if (w + NWAVE * i < MF) {
#pragma unroll
        for (int s = 0; s < 4; ++s)
          acc[s][i] = __builtin_amdgcn_mfma_f32_16x16x32_bf16(af[s], bA[i], acc[s][i], 0, 0, 0);
      }
    __builtin_amdgcn_s_setprio(0);
    if (ks + 2 < KS) {
#pragma unroll
      for (int i = 0; i < NF; ++i)
        if (w + NWAVE * i < MF)
          bA[i] = *(const bf16x8*)(wp + (size_t)((ks + 2) * MF + w + NWAVE * i) * 512);
    }
    af[0] = *(const bf16x8*)(xa0 + ks * 32 + 32);
    af[1] = *(const bf16x8*)(xa1 + ks * 32 + 32);
    af[2] = *(const bf16x8*)(xa2 + ks * 32 + 32);
    af[3] = *(const bf16x8*)(xa3 + ks * 32 + 32);
    __builtin_amdgcn_s_setprio(1);
#pragma unroll
    for (int i = 0; i < NF; ++i)
      if (w + NWAVE * i < MF) {
#pragma unroll
        for (int s = 0; s < 4; ++s)
          acc[s][i] = __builtin_amdgcn_mfma_f32_16x16x32_bf16(af[s], bB[i], acc[s][i], 0, 0, 0);
      }
    __builtin_amdgcn_s_setprio(0);
  }
  __syncthreads();   // all waves done reading X_in
#pragma unroll
  for (int i = 0; i < NF; ++i) {
    const int cb = w + NWAVE * i;
    if (cb < MF) {
      const int col = cb * 16 + lcol;
      const float bc = bias[col];
#pragma unroll
      for (int r = 0; r < 4; ++r) {
        const int p = hi * 4 + r;
        float sp, sg;
        act_sp_sg(acc[0][i][r] + bc, sp, sg);
        X[(0 * 16 + p) * XS + col] = f2bf(sp);
        X[(1 * 16 + p) * XS + col] = f2bf(sg * acc[1][i][r]);
        X[(2 * 16 + p) * XS + col] = f2bf(sg * acc[2][i][r]);
        X[(3 * 16 + p) * XS + col] = f2bf(sg * acc[3][i][r]);
      }
    }
  }
  __syncthreads();
}

// First layer: X rows 0..15 = 16 points x Cin; grads from W[:, :3].
template<int KS, int MF, int COUT>
__device__ __forceinline__ void layer_first(const u16* __restrict__ Wf,
                                            const float* __restrict__ bias,
                                            u16* __restrict__ X,
                                            int w, int lane, int lcol, int hi) {
  constexpr int NF = (MF + NWAVE - 1) / NWAVE;
  f32x4 acc[NF];
#pragma unroll
  for (int i = 0; i < NF; ++i) acc[i] = (f32x4){0.f, 0.f, 0.f, 0.f};
  const u16* wp = Wf + lane * 8;
  const u16* xa0 = X + lcol * XS + hi * 8;
  bf16x8 bA[NF], bB[NF];
#pragma unroll
  for (int i = 0; i < NF; ++i)
    if (w + NWAVE * i < MF)
      bA[i] = *(const bf16x8*)(wp + (size_t)(w + NWAVE * i) * 512);
#pragma unroll 1
  for (int ks = 0; ks < KS; ks += 2) {
#pragma unroll
    for (int i = 0; i < NF; ++i)
      if (w + NWAVE * i < MF)
        bB[i] = *(const bf16x8*)(wp + (size_t)((ks + 1) * MF + w + NWAVE * i) * 512);
    bf16x8 af0 = *(const bf16x8*)(xa0 + ks * 32);
#pragma unroll
    for (int i = 0; i < NF; ++i)
      if (w + NWAVE * i < MF)
        acc[i] = __builtin_amdgcn_mfma_f32_16x16x32_bf16(af0, bA[i], acc[i], 0, 0, 0);
    bf16x8 af1 = *(const bf16x8*)(xa0 + ks * 32 + 32);
    if (ks + 2 < KS) {
#pragma unroll
      for (int i = 0; i < NF; ++i)
        if (w + NWAVE * i < MF)
          bA[i] = *(const bf16x8*)(wp + (size_t)((ks + 2) * MF + w + NWAVE * i) * 512);
    }
#pragma unroll
    for (int i = 0; i < NF; ++i)
      if (w + NWAVE * i < MF)
        acc[i] = __builtin_amdgcn_mfma_f32_16x16x32_bf16(af1, bB[i], acc[i], 0, 0, 0);
  }
  __syncthreads();
#pragma unroll
  for (int i = 0; i < NF; ++i) {
    const int cb = w + NWAVE * i;
    if (cb < MF) {
      const int col = cb * 16 + lcol;
      const bool ok = col < COUT;
      float bc = 0.f, w0 = 0.f, w1 = 0.f, w2 = 0.f;
      if (ok) {
        bc = bias[col];
        const u16* wk = Wf + ((size_t)cb * 64 + lcol) * 8;  // frag ks=0, k=0..2
        w0 = bf2f(wk[0]); w1 = bf2f(wk[1]); w2 = bf2f(wk[2]);
      }
#pragma unroll
      for (int r = 0; r < 4; ++r) {
        const int p = hi * 4 + r;
        float sp = 0.f, sg = 0.f;
        if (ok) act_sp_sg(acc[i][r] + bc, sp, sg);
        X[(0 * 16 + p) * XS + col] = f2bf(sp);
        X[(1 * 16 + p) * XS + col] = f2bf(sg * w0);
        X[(2 * 16 + p) * XS + col] = f2bf(sg * w1);
        X[(3 * 16 + p) * XS + col] = f2bf(sg * w2);
      }
    }
  }
  __syncthreads();
}

__global__ __launch_bounds__(1024, 1)
void fused_net(FusedArgs fa, const u16* __restrict__ WfAll,
               const float* __restrict__ inp, const float* __restrict__ lat,
               float* __restrict__ out, float* __restrict__ outg,
               float* __restrict__ con) {
  __shared__ __align__(16) u16 X[64 * XS];
  __shared__ float fred[NWAVE];
  const int t = threadIdx.x;
  const int w = t >> 6, lane = t & 63;
  const int lcol = lane & 15, hi = lane >> 4;
  const int n0 = blockIdx.x * 16;

  // build x0 in-place: rows 0..15, cols 0..319 (xyz | latent | zero-pad);
  // also emit input_con (f32) for these 16 points.
  for (int c = t; c < 16 * 320; c += 1024) {
    const int row = c / 320, i = c - row * 320;
    const float v = (i < 3) ? inp[(size_t)(n0 + row) * 3 + i]
                  : ((i < 259) ? lat[i - 3] : 0.f);
    X[row * XS + i] = f2bf(v);
    if (i < 259) con[(size_t)(n0 + row) * 259 + i] = v;
  }
  __syncthreads();

  layer_first<10, 36, 515>(WfAll + fa.woff[0],  fa.bias[0],  X, w, lane, lcol, hi);
  layer_mid<18, 32, 512>(WfAll + fa.woff[1],  fa.bias[1],  X, w, lane, lcol, hi);
  layer_mid<16, 32, 512>(WfAll + fa.woff[2],  fa.bias[2],  X, w, lane, lcol, hi);
  layer_mid<16, 36, 576>(WfAll + fa.woff[3],  fa.bias[3],  X, w, lane, lcol, hi);
  layer_mid<18, 36, 576>(WfAll + fa.woff[4],  fa.bias[4],  X, w, lane, lcol, hi);
  layer_mid<18, 48, 768>(WfAll + fa.woff[5],  fa.bias[5],  X, w, lane, lcol, hi);
  layer_mid<24, 48, 768>(WfAll + fa.woff[6],  fa.bias[6],  X, w, lane, lcol, hi);
  layer_mid<24, 48, 768>(WfAll + fa.woff[7],  fa.bias[7],  X, w, lane, lcol, hi);
  layer_mid<24, 60, 960>(WfAll + fa.woff[8],  fa.bias[8],  X, w, lane, lcol, hi);
  layer_mid<30, 60, 960>(WfAll + fa.woff[9],  fa.bias[9],  X, w, lane, lcol, hi);
  layer_mid<30, 56, 896>(WfAll + fa.woff[10], fa.bias[10], X, w, lane, lcol, hi);

  // final c10: weight-norm inline + 64 dots of length 896
  float ss = 0.f;
  for (int k = t; k < 896; k += 1024) { float x = fa.v10[k]; ss += x * x; }
#pragma unroll
  for (int off = 32; off > 0; off >>= 1) ss += __shfl_xor(ss, off);
  if (lane == 0) fred[w] = ss;
  __syncthreads();
  float tot = 0.f;
#pragma unroll
  for (int j = 0; j < NWAVE; ++j) tot += fred[j];
  const float scale = fa.g10[0] / sqrtf(tot);

  for (int id = w; id < 64; id += NWAVE) {
    const int s = id >> 4, p = id & 15;
    const u16* xr = X + (s * 16 + p) * XS;
    float d = 0.f;
#pragma unroll
    for (int j = 0; j < 14; ++j) {
      const int k = lane * 14 + j;
      d += fa.v10[k] * bf2f(xr[k]);
    }
    d *= scale;
#pragma unroll
    for (int off = 32; off > 0; off >>= 1) d += __shfl_xor(d, off);
    if (lane == 0) {
      if (s == 0) out[n0 + p] = d + fa.b10[0];
      else        outg[(size_t)(n0 + p) * 3 + (s - 1)] = d;
    }
  }
}

extern "C" void kernel_launch(void* const* d_in, const int* in_sizes, int n_in,
                              void* d_out, int out_size, void* d_ws, size_t ws_size,
                              hipStream_t stream) {
  static const int CIN [11] = {259,515,512,512,576,576,768,768,768,960,960};
  static const int COUT[11] = {515,512,512,576,576,768,768,768,960,960,896};
  static const int KS  [11] = {10,18,16,16,18,18,24,24,24,30,30};
  static const int MF  [11] = {36,32,32,36,36,48,48,48,60,60,56};

  size_t woff[12]; woff[0] = 0;
  for (int l = 0; l < 11; ++l)
    woff[l + 1] = woff[l] + (size_t)KS[l] * MF[l] * 512;

  u16* Wf = (u16*)d_ws;   // ~11 MB

  float* out_sdf  = (float*)d_out;           // [4096]
  float* out_grad = out_sdf + NPTS;          // [4096][3]
  float* out_con  = out_sdf + NPTS + NPTS*3; // [4096][259]

  WAll wa;
  for (int l = 0; l < 11; ++l) {
    wa.L[l].v = (const float*)d_in[2 + 3 * l];
    wa.L[l].g = (const float*)d_in[3 + 3 * l];
    wa.L[l].Cin = CIN[l]; wa.L[l].Cout = COUT[l];
    wa.L[l].KS = KS[l]; wa.L[l].MF = MF[l];
    wa.L[l].woff = woff[l];
  }
  wnormF<<<dim3(60, 11), dim3(256), 0, stream>>>(wa, Wf);

  FusedArgs fa;
  for (int l = 0; l < 11; ++l) {
    fa.woff[l] = woff[l];
    fa.bias[l] = (const float*)d_in[4 + 3 * l];
  }
  fa.v10 = (const float*)d_in[35];
  fa.g10 = (const float*)d_in[36];
  fa.b10 = (const float*)d_in[37];

  fused_net<<<dim3(NPTS / 16), dim3(1024), 0, stream>>>(
      fa, Wf, (const float*)d_in[0], (const float*)d_in[1],
      out_sdf, out_grad, out_con);
}

// Round 19
// 205.526 us; speedup vs baseline: 1.1226x; 1.1226x over previous
//
#include <hip/hip_runtime.h>
#include <hip/hip_bf16.h>

// Network_70918499991665: 12-layer implicit-map extractor, fwd + analytic grad.
// Round 18: r16 base (spill-clean loop, 1024 thr, setprio) +
// (a) per-layer frag-assignment ROTATION to balance remainder frags across
//     waves (critical MFMA path 2846 -> 2676, -6%),
// (b) epilogue bf16 conversion via v_cvt_pk_bf16_f32 (HW RNE, 1 instr/pair vs
//     ~4 VALU per value of manual bit-math).

#define NPTS 4096
#define XS 968          // X LDS row stride in u16

typedef unsigned short u16;
typedef unsigned int   u32;
typedef __attribute__((ext_vector_type(8))) __bf16 bf16x8;
typedef __attribute__((ext_vector_type(4))) float  f32x4;

__device__ __forceinline__ float bf2f(u16 h) {
  return __uint_as_float(((u32)h) << 16);
}
__device__ __forceinline__ u16 f2bf(float f) {
  u32 u = __float_as_uint(f);
  u += 0x7fff + ((u >> 16) & 1);   // RNE
  return (u16)(u >> 16);
}
__device__ __forceinline__ u32 cvt_pk_bf16(float lo, float hi) {
  u32 r;
  asm("v_cvt_pk_bf16_f32 %0, %1, %2" : "=v"(r) : "v"(lo), "v"(hi));
  return r;
}

// softplus(100x)/100 and sigmoid(100x), numerically stable
__device__ __forceinline__ void act_sp_sg(float pre, float& sp, float& sg) {
  float z = 100.f * pre;
  float e = __expf(-fabsf(z));
  float r = 1.f / (1.f + e);
  float l = __logf(1.f + e) * 0.01f;
  if (z >= 0.f) { sg = r;       sp = pre + l; }
  else          { sg = 1.f - r; sp = l; }
}

// ---------------- weight-norm + pack into MFMA B-fragment order.
struct WLayer { const float* v; const float* g; int Cin, Cout, KS, MF; size_t woff; };
struct WAll { WLayer L[11]; };

__global__ __launch_bounds__(256)
void wnormF(WAll wa, u16* __restrict__ Wf) {
  const WLayer L = wa.L[blockIdx.y];
  const int cb = blockIdx.x;
  if (cb >= L.MF) return;
  __shared__ float red[16][17];
  __shared__ float scl[16];
  const int t = threadIdx.x;
  {
    const int col16 = t >> 4, kt = t & 15;
    const int col = cb * 16 + col16;
    float ss = 0.f;
    if (col < L.Cout)
      for (int k = kt; k < L.Cin; k += 16) {
        float x = L.v[(size_t)col * L.Cin + k]; ss += x * x;
      }
    red[col16][kt] = ss;
  }
  __syncthreads();
  if (t < 16) {
    float s = 0.f;
#pragma unroll
    for (int j = 0; j < 16; ++j) s += red[t][j];
    const int c = cb * 16 + t;
    scl[t] = (c < L.Cout) ? L.g[c] / sqrtf(s) : 0.f;
  }
  __syncthreads();
  u32* dst = (u32*)(Wf + L.woff);
  const int lane = t >> 2, q = t & 3;
  const int vcol = cb * 16 + (lane & 15);
  const float sc = scl[lane & 15];
  const float* vrow = L.v + (size_t)vcol * L.Cin;
  const bool cok = vcol < L.Cout;
  for (int ks = 0; ks < L.KS; ++ks) {
    const int k0 = ks * 32 + (lane >> 4) * 8 + q * 2;
    u16 lo = 0, hi16 = 0;
    if (cok) {
      if (k0 < L.Cin)     lo   = f2bf(vrow[k0] * sc);
      if (k0 + 1 < L.Cin) hi16 = f2bf(vrow[k0 + 1] * sc);
    }
    dst[(size_t)(ks * L.MF + cb) * 128 + t] = (u32)lo | ((u32)hi16 << 16);
  }
}

// ---------------- fused network ----------------
#define NWAVE 16
struct FusedArgs {
  size_t woff[11];
  const float* bias[11];
  const float* v10; const float* g10; const float* b10;
};

// Mid layer. ROT rotates the remainder-frag assignment across waves.
template<int KS, int MF, int COUT, int ROT>
__device__ __forceinline__ void layer_mid(const u16* __restrict__ Wf,
                                          const float* __restrict__ bias,
                                          u16* __restrict__ X,
                                          int w, int lane, int lcol, int hi) {
  static_assert(COUT == MF * 16, "mid layers have exact tiling");
  constexpr int NF = (MF + NWAVE - 1) / NWAVE;
  const int wr = (w + ROT) & 15;          // rotated frag base
  f32x4 acc[4][NF];
#pragma unroll
  for (int s = 0; s < 4; ++s)
#pragma unroll
    for (int i = 0; i < NF; ++i) acc[s][i] = (f32x4){0.f, 0.f, 0.f, 0.f};

  const u16* wp = Wf + lane * 8;
  const u16* xa0 = X + lcol * XS + hi * 8;
  const u16* xa1 = xa0 + 16 * XS;
  const u16* xa2 = xa0 + 32 * XS;
  const u16* xa3 = xa0 + 48 * XS;
  bf16x8 bA[NF], bB[NF];
#pragma unroll
  for (int i = 0; i < NF; ++i)
    if (wr + NWAVE * i < MF)
      bA[i] = *(const bf16x8*)(wp + (size_t)(wr + NWAVE * i) * 512);

#pragma unroll 1
  for (int ks = 0; ks < KS; ks += 2) {
    bf16x8 af[4];
    af[0] = *(const bf16x8*)(xa0 + ks * 32);
    af[1] = *(const bf16x8*)(xa1 + ks * 32);
    af[2] = *(const bf16x8*)(xa2 + ks * 32);
    af[3] = *(const bf16x8*)(xa3 + ks * 32);
#pragma unroll
    for (int i = 0; i < NF; ++i)
      if (wr + NWAVE * i < MF)
        bB[i] = *(const bf16x8*)(wp + (size_t)((ks + 1) * MF + wr + NWAVE * i) * 512);
    __builtin_amdgcn_s_setprio(1);
#pragma unroll
    for (int i = 0; i < NF; ++i)
      if (wr + NWAVE * i < MF) {
#pragma unroll
        for (int s = 0; s < 4; ++s)
          acc[s][i] = __builtin_amdgcn_mfma_f32_16x16x32_bf16(af[s], bA[i], acc[s][i], 0, 0, 0);
      }
    __builtin_amdgcn_s_setprio(0);
    af[0] = *(const bf16x8*)(xa0 + ks * 32 + 32);
    af[1] = *(const bf16x8*)(xa1 + ks * 32 + 32);
    af[2] = *(const bf16x8*)(xa2 + ks * 32 + 32);
    af[3] = *(const bf16x8*)(xa3 + ks * 32 + 32);
    if (ks + 2 < KS) {
#pragma unroll
      for (int i = 0; i < NF; ++i)
        if (wr + NWAVE * i < MF)
          bA[i] = *(const bf16x8*)(wp + (size_t)((ks + 2) * MF + wr + NWAVE * i) * 512);
    }
    __builtin_amdgcn_s_setprio(1);
#pragma unroll
    for (int i = 0; i < NF; ++i)
      if (wr + NWAVE * i < MF) {
#pragma unroll
        for (int s = 0; s < 4; ++s)
          acc[s][i] = __builtin_amdgcn_mfma_f32_16x16x32_bf16(af[s], bB[i], acc[s][i], 0, 0, 0);
      }
    __builtin_amdgcn_s_setprio(0);
  }
  __syncthreads();   // all waves done reading X_in
#pragma unroll
  for (int i = 0; i < NF; ++i) {
    const int cb = wr + NWAVE * i;
    if (cb < MF) {
      const int col = cb * 16 + lcol;
      const float bc = bias[col];
      float sp[4], sg[4];
#pragma unroll
      for (int r = 0; r < 4; ++r) act_sp_sg(acc[0][i][r] + bc, sp[r], sg[r]);
      const int p0 = hi * 4;
      u16* x0p = X + (0 * 16 + p0) * XS + col;
      u16* x1p = X + (1 * 16 + p0) * XS + col;
      u16* x2p = X + (2 * 16 + p0) * XS + col;
      u16* x3p = X + (3 * 16 + p0) * XS + col;
      u32 pk;
      pk = cvt_pk_bf16(sp[0], sp[1]);
      x0p[0] = (u16)pk; x0p[XS] = (u16)(pk >> 16);
      pk = cvt_pk_bf16(sp[2], sp[3]);
      x0p[2 * XS] = (u16)pk; x0p[3 * XS] = (u16)(pk >> 16);
      pk = cvt_pk_bf16(sg[0] * acc[1][i][0], sg[1] * acc[1][i][1]);
      x1p[0] = (u16)pk; x1p[XS] = (u16)(pk >> 16);
      pk = cvt_pk_bf16(sg[2] * acc[1][i][2], sg[3] * acc[1][i][3]);
      x1p[2 * XS] = (u16)pk; x1p[3 * XS] = (u16)(pk >> 16);
      pk = cvt_pk_bf16(sg[0] * acc[2][i][0], sg[1] * acc[2][i][1]);
      x2p[0] = (u16)pk; x2p[XS] = (u16)(pk >> 16);
      pk = cvt_pk_bf16(sg[2] * acc[2][i][2], sg[3] * acc[2][i][3]);
      x2p[2 * XS] = (u16)pk; x2p[3 * XS] = (u16)(pk >> 16);
      pk = cvt_pk_bf16(sg[0] * acc[3][i][0], sg[1] * acc[3][i][1]);
      x3p[0] = (u16)pk; x3p[XS] = (u16)(pk >> 16);
      pk = cvt_pk_bf16(sg[2] * acc[3][i][2], sg[3] * acc[3][i][3]);
      x3p[2 * XS] = (u16)pk; x3p[3 * XS] = (u16)(pk >> 16);
    }
  }
  __syncthreads();
}

// First layer: X rows 0..15 = 16 points x Cin; grads from W[:, :3].
template<int KS, int MF, int COUT, int ROT>
__device__ __forceinline__ void layer_first(const u16* __restrict__ Wf,
                                            const float* __restrict__ bias,
                                            u16* __restrict__ X,
                                            int w, int lane, int lcol, int hi) {
  constexpr int NF = (MF + NWAVE - 1) / NWAVE;
  const int wr = (w + ROT) & 15;
  f32x4 acc[NF];
#pragma unroll
  for (int i = 0; i < NF; ++i) acc[i] = (f32x4){0.f, 0.f, 0.f, 0.f};
  const u16* wp = Wf + lane * 8;
  const u16* xa0 = X + lcol * XS + hi * 8;
  bf16x8 bA[NF], bB[NF];
#pragma unroll
  for (int i = 0; i < NF; ++i)
    if (wr + NWAVE * i < MF)
      bA[i] = *(const bf16x8*)(wp + (size_t)(wr + NWAVE * i) * 512);
#pragma unroll 1
  for (int ks = 0; ks < KS; ks += 2) {
    bf16x8 af0 = *(const bf16x8*)(xa0 + ks * 32);
#pragma unroll
    for (int i = 0; i < NF; ++i)
      if (wr + NWAVE * i < MF)
        bB[i] = *(const bf16x8*)(wp + (size_t)((ks + 1) * MF + wr + NWAVE * i) * 512);
#pragma unroll
    for (int i = 0; i < NF; ++i)
      if (wr + NWAVE * i < MF)
        acc[i] = __builtin_amdgcn_mfma_f32_16x16x32_bf16(af0, bA[i], acc[i], 0, 0, 0);
    bf16x8 af1 = *(const bf16x8*)(xa0 + ks * 32 + 32);
    if (ks + 2 < KS) {
#pragma unroll
      for (int i = 0; i < NF; ++i)
        if (wr + NWAVE * i < MF)
          bA[i] = *(const bf16x8*)(wp + (size_t)((ks + 2) * MF + wr + NWAVE * i) * 512);
    }
#pragma unroll
    for (int i = 0; i < NF; ++i)
      if (wr + NWAVE * i < MF)
        acc[i] = __builtin_amdgcn_mfma_f32_16x16x32_bf16(af1, bB[i], acc[i], 0, 0, 0);
  }
  __syncthreads();
#pragma unroll
  for (int i = 0; i < NF; ++i) {
    const int cb = wr + NWAVE * i;
    if (cb < MF) {
      const int col = cb * 16 + lcol;
      const bool ok = col < COUT;
      float bc = 0.f, w0 = 0.f, w1 = 0.f, w2 = 0.f;
      if (ok) {
        bc = bias[col];
        const u16* wk = Wf + ((size_t)cb * 64 + lcol) * 8;  // frag ks=0, k=0..2
        w0 = bf2f(wk[0]); w1 = bf2f(wk[1]); w2 = bf2f(wk[2]);
      }
#pragma unroll
      for (int r = 0; r < 4; ++r) {
        const int p = hi * 4 + r;
        float sp = 0.f, sg = 0.f;
        if (ok) act_sp_sg(acc[i][r] + bc, sp, sg);
        X[(0 * 16 + p) * XS + col] = f2bf(sp);
        X[(1 * 16 + p) * XS + col] = f2bf(sg * w0);
        X[(2 * 16 + p) * XS + col] = f2bf(sg * w1);
        X[(3 * 16 + p) * XS + col] = f2bf(sg * w2);
      }
    }
  }
  __syncthreads();
}

__global__ __launch_bounds__(1024, 1)
void fused_net(FusedArgs fa, const u16* __restrict__ WfAll,
               const float* __restrict__ inp, const float* __restrict__ lat,
               float* __restrict__ out, float* __restrict__ outg,
               float* __restrict__ con) {
  __shared__ __align__(16) u16 X[64 * XS];
  __shared__ float fred[NWAVE];
  const int t = threadIdx.x;
  const int w = t >> 6, lane = t & 63;
  const int lcol = lane & 15, hi = lane >> 4;
  const int n0 = blockIdx.x * 16;

  // build x0 in-place; also emit input_con (f32) for these 16 points.
  for (int c = t; c < 16 * 320; c += 1024) {
    const int row = c / 320, i = c - row * 320;
    const float v = (i < 3) ? inp[(size_t)(n0 + row) * 3 + i]
                  : ((i < 259) ? lat[i - 3] : 0.f);
    X[row * XS + i] = f2bf(v);
    if (i < 259) con[(size_t)(n0 + row) * 259 + i] = v;
  }
  __syncthreads();

  // Rotations balance remainder frags: relieved waves per layer —
  // L8(ROT=4)->w4-7 relieved, L9(ROT=12)->w0-3, L10(ROT=8)->w8-15;
  // burdens: L0(ROT=8)->w8-11, L3(ROT=0)->w0-3, L4(ROT=12)->w4-7.
  layer_first<10, 36, 515, 8>(WfAll + fa.woff[0],  fa.bias[0],  X, w, lane, lcol, hi);
  layer_mid<18, 32, 512, 0>(WfAll + fa.woff[1],  fa.bias[1],  X, w, lane, lcol, hi);
  layer_mid<16, 32, 512, 0>(WfAll + fa.woff[2],  fa.bias[2],  X, w, lane, lcol, hi);
  layer_mid<16, 36, 576, 0>(WfAll + fa.woff[3],  fa.bias[3],  X, w, lane, lcol, hi);
  layer_mid<18, 36, 576, 12>(WfAll + fa.woff[4],  fa.bias[4],  X, w, lane, lcol, hi);
  layer_mid<18, 48, 768, 0>(WfAll + fa.woff[5],  fa.bias[5],  X, w, lane, lcol, hi);
  layer_mid<24, 48, 768, 0>(WfAll + fa.woff[6],  fa.bias[6],  X, w, lane, lcol, hi);
  layer_mid<24, 48, 768, 0>(WfAll + fa.woff[7],  fa.bias[7],  X, w, lane, lcol, hi);
  layer_mid<24, 60, 960, 4>(WfAll + fa.woff[8],  fa.bias[8],  X, w, lane, lcol, hi);
  layer_mid<30, 60, 960, 12>(WfAll + fa.woff[9],  fa.bias[9],  X, w, lane, lcol, hi);
  layer_mid<30, 56, 896, 8>(WfAll + fa.woff[10], fa.bias[10], X, w, lane, lcol, hi);

  // final c10: weight-norm inline + 64 dots of length 896
  float ss = 0.f;
  for (int k = t; k < 896; k += 1024) { float x = fa.v10[k]; ss += x * x; }
#pragma unroll
  for (int off = 32; off > 0; off >>= 1) ss += __shfl_xor(ss, off);
  if (lane == 0) fred[w] = ss;
  __syncthreads();
  float tot = 0.f;
#pragma unroll
  for (int j = 0; j < NWAVE; ++j) tot += fred[j];
  const float scale = fa.g10[0] / sqrtf(tot);

  for (int id = w; id < 64; id += NWAVE) {
    const int s = id >> 4, p = id & 15;
    const u16* xr = X + (s * 16 + p) * XS;
    float d = 0.f;
#pragma unroll
    for (int j = 0; j < 14; ++j) {
      const int k = lane * 14 + j;
      d += fa.v10[k] * bf2f(xr[k]);
    }
    d *= scale;
#pragma unroll
    for (int off = 32; off > 0; off >>= 1) d += __shfl_xor(d, off);
    if (lane == 0) {
      if (s == 0) out[n0 + p] = d + fa.b10[0];
      else        outg[(size_t)(n0 + p) * 3 + (s - 1)] = d;
    }
  }
}

extern "C" void kernel_launch(void* const* d_in, const int* in_sizes, int n_in,
                              void* d_out, int out_size, void* d_ws, size_t ws_size,
                              hipStream_t stream) {
  static const int CIN [11] = {259,515,512,512,576,576,768,768,768,960,960};
  static const int COUT[11] = {515,512,512,576,576,768,768,768,960,960,896};
  static const int KS  [11] = {10,18,16,16,18,18,24,24,24,30,30};
  static const int MF  [11] = {36,32,32,36,36,48,48,48,60,60,56};

  size_t woff[12]; woff[0] = 0;
  for (int l = 0; l < 11; ++l)
    woff[l + 1] = woff[l] + (size_t)KS[l] * MF[l] * 512;

  u16* Wf = (u16*)d_ws;   // ~11 MB

  float* out_sdf  = (float*)d_out;           // [4096]
  float* out_grad = out_sdf + NPTS;          // [4096][3]
  float* out_con  = out_sdf + NPTS + NPTS*3; // [4096][259]

  WAll wa;
  for (int l = 0; l < 11; ++l) {
    wa.L[l].v = (const float*)d_in[2 + 3 * l];
    wa.L[l].g = (const float*)d_in[3 + 3 * l];
    wa.L[l].Cin = CIN[l]; wa.L[l].Cout = COUT[l];
    wa.L[l].KS = KS[l]; wa.L[l].MF = MF[l];
    wa.L[l].woff = woff[l];
  }
  wnormF<<<dim3(60, 11), dim3(256), 0, stream>>>(wa, Wf);

  FusedArgs fa;
  for (int l = 0; l < 11; ++l) {
    fa.woff[l] = woff[l];
    fa.bias[l] = (const float*)d_in[4 + 3 * l];
  }
  fa.v10 = (const float*)d_in[35];
  fa.g10 = (const float*)d_in[36];
  fa.b10 = (const float*)d_in[37];

  fused_net<<<dim3(NPTS / 16), dim3(1024), 0, stream>>>(
      fa, Wf, (const float*)d_in[0], (const float*)d_in[1],
      out_sdf, out_grad, out_con);
}